// Round 1
// 84.497 us; speedup vs baseline: 1.3000x; 1.3000x over previous
//
#include <hip/hip_runtime.h>

#define BN_EPS 1e-5f

typedef const float* fp;
typedef float f32x4 __attribute__((ext_vector_type(4)));
typedef _Float16 f16x4 __attribute__((ext_vector_type(4)));

// fast transcendentals: identical formulas to the previous (passing) kernel.
__device__ __forceinline__ float frcp(float x) { return __builtin_amdgcn_rcpf(x); }
__device__ __forceinline__ float sigm(float x) { return frcp(1.0f + __expf(-x)); }
__device__ __forceinline__ float tanh_fast(float x) { return 1.0f - 2.0f * frcp(1.0f + __expf(2.0f * x)); }

__device__ __forceinline__ f32x4 ld4(const float* p) { return *(const f32x4*)p; }
__device__ __forceinline__ float dot4(f32x4 a, f32x4 b) {
    return a[0] * b[0] + a[1] * b[1] + a[2] * b[2] + a[3] * b[3];
}

#define MFMA16(A, B, C) __builtin_amdgcn_mfma_f32_16x16x16f16((A), (B), (C), 0, 0, 0)

// ---------------------------------------------------------------------------
// K1: fold item/cat embedding tables through Wih; zero the BN stats accums.
// P_cat rows padded to 52 floats (bank-spread for ds_read_b128) and carry
// bih (+ bhh for the r,z gates). bhn stays separate (multiplied by r).
// ---------------------------------------------------------------------------
__global__ __launch_bounds__(256) void k_precompute(
    fp Wih, fp bih, fp bhh, fp item_table, fp cat_table,
    float* __restrict__ P_item, float* __restrict__ P_cat,
    float* __restrict__ stats, int nItemElems, int nItemBlocks)
{
    __shared__ float w[768];
    for (int t = threadIdx.x; t < 768; t += blockDim.x) w[t] = Wih[t];
    __syncthreads();

    if ((int)blockIdx.x < nItemBlocks) {
        int idx = blockIdx.x * blockDim.x + threadIdx.x;
        if (idx < nItemElems) {
            int i = idx / 48, g = idx % 48;
            const float* row = item_table + (size_t)i * 12;
            float acc = 0.f;
#pragma unroll
            for (int k = 0; k < 12; ++k) acc += w[g * 16 + k] * row[k];
            P_item[idx] = acc;
        }
    } else {
        for (int t = threadIdx.x; t < 480; t += blockDim.x) {
            int c = t / 48, g = t % 48;
            float acc = bih[g] + (g < 32 ? bhh[g] : 0.f);
#pragma unroll
            for (int k = 0; k < 4; ++k) acc += w[g * 16 + 12 + k] * cat_table[c * 4 + k];
            P_cat[c * 52 + g] = acc;
        }
        if (threadIdx.x < 128) stats[threadIdx.x] = 0.f;   // stats1[96] + stats2[32]
    }
}

// ---------------------------------------------------------------------------
// K2: MFMA GRU. One wave = 16 samples. Lane l: sample s=l&15, hi=l>>4.
// MFMA 16x16x16 f16:  A[m][k]: lane holds row m=s, k=4hi+i (Whh gate block)
//                     B[k][n]: lane holds k=4hi+i, col n=s (hidden state h)
//                     D[m][n]: lane holds m=4hi+q, col n=s
// => D (h_new, dims 4hi+q of sample s) IS the next step's B fragment. No
// cross-lane traffic in the recurrence. Split-f16: W*h ~= Wh*hh + Wl*hh + Wh*hl.
// ---------------------------------------------------------------------------
__global__ __launch_bounds__(256) void k_gru(
    const int* __restrict__ user_id, const int* __restrict__ hist_item,
    const int* __restrict__ hist_cat, const int* __restrict__ tgt_item,
    const int* __restrict__ tgt_cat,
    fp user_table, fp item_table, fp cat_table,
    fp Whh, fp bhh,
    fp mha_Win, fp mha_bin, fp mha_Wout, fp mha_bout,
    const float* __restrict__ P_item, const float* __restrict__ P_cat,
    float* __restrict__ all_enc, float* __restrict__ stats1, int B, int T)
{
    __shared__ float s_pcat[520];       // 10 cats x 52 (padded)
    __shared__ float lds_part[4][96];

    const int tid  = threadIdx.x;
    const int lane = tid & 63;
    const int wid  = tid >> 6;
    const int s    = lane & 15;     // sample slot within wave
    const int hi   = lane >> 4;     // 4-dim group owned by this lane

    long b = ((long)blockIdx.x * 4 + wid) * 16 + s;
    const bool act = (b < B);
    if (!act) b = B - 1;            // clamp: loads stay valid, stores masked

    for (int t = tid; t < 520; t += 256) s_pcat[t] = P_cat[t];

    // Whh A-fragments (row = s, k = 4hi+i) per gate block, split into f16 hi/lo
    f32x4 wrf = ld4(&Whh[(0  + s) * 16 + 4 * hi]);
    f32x4 wzf = ld4(&Whh[(16 + s) * 16 + 4 * hi]);
    f32x4 wnf = ld4(&Whh[(32 + s) * 16 + 4 * hi]);
    f16x4 wr_h = __builtin_convertvector(wrf, f16x4);
    f16x4 wz_h = __builtin_convertvector(wzf, f16x4);
    f16x4 wn_h = __builtin_convertvector(wnf, f16x4);
    f16x4 wr_l = __builtin_convertvector(wrf - __builtin_convertvector(wr_h, f32x4), f16x4);
    f16x4 wz_l = __builtin_convertvector(wzf - __builtin_convertvector(wz_h, f32x4), f16x4);
    f16x4 wn_l = __builtin_convertvector(wnf - __builtin_convertvector(wn_h, f32x4), f16x4);
    const f32x4 bhn4 = ld4(&bhh[32 + 4 * hi]);   // C-init of the n-gate MFMA

    const int* ip = hist_item + b * T;
    const int* cp = hist_cat  + b * T;

    f32x4 h    = {0.f, 0.f, 0.f, 0.f};
    f32x4 hsum = {0.f, 0.f, 0.f, 0.f};
    f16x4 h_h = {}, h_l = {};

    __syncthreads();   // s_pcat ready

    // prologue: x-gates for t=0, ids prefetched one step further
    int id0 = ip[0], cd0 = cp[0];
    const float* pi0 = P_item + (long)id0 * 48;
    int pb0 = cd0 * 52;
    f32x4 pir = ld4(pi0 + 4 * hi), piz = ld4(pi0 + 16 + 4 * hi), pin = ld4(pi0 + 32 + 4 * hi);
    f32x4 pcr = ld4(&s_pcat[pb0 + 4 * hi]);
    f32x4 pcz = ld4(&s_pcat[pb0 + 16 + 4 * hi]);
    f32x4 pcn = ld4(&s_pcat[pb0 + 32 + 4 * hi]);
    int tnext = (T > 1) ? 1 : 0;
    int idn = ip[tnext], cdn = cp[tnext];

    for (int t = 0; t < T; ++t) {
        f32x4 xr = pir + pcr, xz = piz + pcz, xn = pin + pcn;
        if (t + 1 < T) {
            // issue next step's x loads now (covered by this step's compute)
            const float* pi = P_item + (long)idn * 48;
            int pb = cdn * 52;
            pir = ld4(pi + 4 * hi); piz = ld4(pi + 16 + 4 * hi); pin = ld4(pi + 32 + 4 * hi);
            pcr = ld4(&s_pcat[pb + 4 * hi]);
            pcz = ld4(&s_pcat[pb + 16 + 4 * hi]);
            pcn = ld4(&s_pcat[pb + 32 + 4 * hi]);
            int tn = (t + 2 < T) ? t + 2 : T - 1;   // ids two steps ahead
            idn = ip[tn]; cdn = cp[tn];
        }

        f32x4 aR = MFMA16(wr_h, h_h, xr);
        aR = MFMA16(wr_l, h_h, aR);
        aR = MFMA16(wr_h, h_l, aR);
        f32x4 aZ = MFMA16(wz_h, h_h, xz);
        aZ = MFMA16(wz_l, h_h, aZ);
        aZ = MFMA16(wz_h, h_l, aZ);
        f32x4 aN = MFMA16(wn_h, h_h, bhn4);
        aN = MFMA16(wn_l, h_h, aN);
        aN = MFMA16(wn_h, h_l, aN);

#pragma unroll
        for (int q = 0; q < 4; ++q) {
            float r = sigm(aR[q]);
            float z = sigm(aZ[q]);
            float n = tanh_fast(fmaf(r, aN[q], xn[q]));
            h[q] = z * (h[q] - n) + n;
        }
        hsum += h;
        h_h = __builtin_convertvector(h, f16x4);
        h_l = __builtin_convertvector(h - __builtin_convertvector(h_h, f32x4), f16x4);
    }

    // ---- epilogue: degenerate MHA -> A[b], all_enc row, BN1 stats ----
    int ti = tgt_item[b], tc = tgt_cat[b];
    const float* itr = item_table + (size_t)ti * 12;
    f32x4 tv0 = ld4(itr), tv1 = ld4(itr + 4), tv2 = ld4(itr + 8);
    f32x4 tv3 = ld4(cat_table + tc * 4);

    // v = Wv @ tgt + bv  (rows 32..47 of mha_Win); lane computes dims 4hi+q
    f32x4 vq;
#pragma unroll
    for (int q = 0; q < 4; ++q) {
        int row = 32 + 4 * hi + q;
        const float* wv = mha_Win + row * 16;
        vq[q] = mha_bin[row] + dot4(ld4(wv), tv0) + dot4(ld4(wv + 4), tv1)
              + dot4(ld4(wv + 8), tv2) + dot4(ld4(wv + 12), tv3);
    }
    // gather full v[16] of this sample from the 4 hi-groups (lanes s+16g)
    f32x4 vg0, vg1, vg2, vg3;
#pragma unroll
    for (int q = 0; q < 4; ++q) {
        vg0[q] = __shfl_xor(vq[q], (hi ^ 0) << 4);
        vg1[q] = __shfl_xor(vq[q], (hi ^ 1) << 4);
        vg2[q] = __shfl_xor(vq[q], (hi ^ 2) << 4);
        vg3[q] = __shfl_xor(vq[q], (hi ^ 3) << 4);
    }
    f32x4 aj;
#pragma unroll
    for (int q = 0; q < 4; ++q) {
        int row = 4 * hi + q;
        const float* wo = mha_Wout + row * 16;
        aj[q] = mha_bout[row] + dot4(ld4(wo), vg0) + dot4(ld4(wo + 4), vg1)
              + dot4(ld4(wo + 8), vg2) + dot4(ld4(wo + 12), vg3);
    }
    f32x4 avg = aj * hsum;

    int uid = user_id[b];
    f32x4 u4 = ld4(user_table + (size_t)uid * 16 + 4 * hi);
    f32x4 t4 = (hi == 0) ? tv0 : (hi == 1) ? tv1 : (hi == 2) ? tv2 : tv3;

    if (act) {
        float* er = all_enc + b * 48 + 4 * hi;
        *(f32x4*)er        = avg;
        *(f32x4*)(er + 16) = t4;
        *(f32x4*)(er + 32) = u4;
    }

    f32x4 sa = avg, st = t4, su = u4;
    if (!act) {
        sa = (f32x4){0.f, 0.f, 0.f, 0.f};
        st = (f32x4){0.f, 0.f, 0.f, 0.f};
        su = (f32x4){0.f, 0.f, 0.f, 0.f};
    }
    f32x4 qa = sa * sa, qt = st * st, qu = su * su;
    // reduce over the 16 samples of this wave (xor over lane&15)
#pragma unroll
    for (int m = 1; m <= 8; m <<= 1) {
#pragma unroll
        for (int q = 0; q < 4; ++q) {
            sa[q] += __shfl_xor(sa[q], m);
            st[q] += __shfl_xor(st[q], m);
            su[q] += __shfl_xor(su[q], m);
            qa[q] += __shfl_xor(qa[q], m);
            qt[q] += __shfl_xor(qt[q], m);
            qu[q] += __shfl_xor(qu[q], m);
        }
    }
    if (s == 0) {
        int c = 4 * hi;
#pragma unroll
        for (int q = 0; q < 4; ++q) {
            lds_part[wid][c + q]      = sa[q];
            lds_part[wid][16 + c + q] = st[q];
            lds_part[wid][32 + c + q] = su[q];
            lds_part[wid][48 + c + q] = qa[q];
            lds_part[wid][64 + c + q] = qt[q];
            lds_part[wid][80 + c + q] = qu[q];
        }
    }
    __syncthreads();
    if (tid < 96) {
        float v = lds_part[0][tid] + lds_part[1][tid] + lds_part[2][tid] + lds_part[3][tid];
        atomicAdd(&stats1[tid], v);
    }
}

// ---------------------------------------------------------------------------
// K3: finalize BN1 stats, fold BN1 into fc1 -> W1f[16][48], b1f[16]
// ---------------------------------------------------------------------------
__global__ void k_fold1(const float* __restrict__ stats, fp fc1_W, fp fc1_b,
                        fp g1, fp b1, float* __restrict__ W1f,
                        float* __restrict__ b1f, int B)
{
    __shared__ float kk[48], mm[48];
    int t = threadIdx.x;
    if (t < 48) {
        float mu  = stats[t] / (float)B;
        float var = stats[48 + t] / (float)B - mu * mu;
        float k   = rsqrtf(var + BN_EPS);
        float gk  = g1[t] * k;
        kk[t] = gk;
        mm[t] = b1[t] - mu * gk;
    }
    __syncthreads();
    for (int idx = t; idx < 768; idx += blockDim.x) {
        int c = idx % 48;
        W1f[idx] = fc1_W[idx] * kk[c];
    }
    if (t < 16) {
        float acc = fc1_b[t];
        for (int c = 0; c < 48; ++c) acc += fc1_W[t * 48 + c] * mm[c];
        b1f[t] = acc;
    }
}

// ---------------------------------------------------------------------------
// K4: h = relu(W1f @ all_enc + b1f), store h[B][16], accumulate BN2 stats
// ---------------------------------------------------------------------------
__global__ __launch_bounds__(256) void k_fc1(
    const float* __restrict__ all_enc, const float* __restrict__ W1f,
    const float* __restrict__ b1f, float* __restrict__ hbuf,
    float* __restrict__ stats2, int B)
{
    const int tid = threadIdx.x, lane = tid & 63, wid = tid >> 6;
    const int j = lane & 15, sl = lane >> 4;
    __shared__ float part[4][32];

    float w[48];
#pragma unroll
    for (int q = 0; q < 12; ++q) {
        float4 v = *(const float4*)&W1f[j * 48 + q * 4];
        w[q * 4 + 0] = v.x; w[q * 4 + 1] = v.y; w[q * 4 + 2] = v.z; w[q * 4 + 3] = v.w;
    }
    const float bj = b1f[j];

    float sh = 0.f, sq = 0.f;
    for (long b = (long)blockIdx.x * 16 + wid * 4 + sl; b < B; b += (long)gridDim.x * 16) {
        const float* x = all_enc + b * 48;
        float acc = bj;
#pragma unroll
        for (int q = 0; q < 12; ++q) {
            float4 v = *(const float4*)&x[q * 4];
            acc += w[q * 4] * v.x + w[q * 4 + 1] * v.y + w[q * 4 + 2] * v.z + w[q * 4 + 3] * v.w;
        }
        float h = fmaxf(acc, 0.f);
        hbuf[b * 16 + j] = h;
        sh += h; sq += h * h;
    }
    sh += __shfl_xor(sh, 16); sh += __shfl_xor(sh, 32);
    sq += __shfl_xor(sq, 16); sq += __shfl_xor(sq, 32);
    if (sl == 0) { part[wid][j] = sh; part[wid][16 + j] = sq; }
    __syncthreads();
    if (tid < 32) {
        float v = part[0][tid] + part[1][tid] + part[2][tid] + part[3][tid];
        atomicAdd(&stats2[tid], v);
    }
}

// ---------------------------------------------------------------------------
// K5: finalize BN2 stats, fold BN2 into fc2 -> W2f[2][16], b2f[2]
// ---------------------------------------------------------------------------
__global__ void k_fold2(const float* __restrict__ stats2, fp fc2_W, fp fc2_b,
                        fp g2, fp b2, float* __restrict__ W2f,
                        float* __restrict__ b2fv, int B)
{
    __shared__ float kk[16], mm[16];
    int t = threadIdx.x;
    if (t < 16) {
        float mu  = stats2[t] / (float)B;
        float var = stats2[16 + t] / (float)B - mu * mu;
        float k   = rsqrtf(var + BN_EPS);
        float gk  = g2[t] * k;
        kk[t] = gk;
        mm[t] = b2[t] - mu * gk;
    }
    __syncthreads();
    if (t < 32) W2f[t] = fc2_W[t] * kk[t & 15];
    if (t < 2) {
        float acc = fc2_b[t];
        for (int c = 0; c < 16; ++c) acc += fc2_W[t * 16 + c] * mm[c];
        b2fv[t] = acc;
    }
}

// ---------------------------------------------------------------------------
// K6: logits + softmax -> f32 out[B][2]
// ---------------------------------------------------------------------------
__global__ __launch_bounds__(256) void k_out(
    const float* __restrict__ hbuf, const float* __restrict__ W2f,
    const float* __restrict__ b2fv, float* __restrict__ out, int B)
{
    __shared__ float w[34];
    if (threadIdx.x < 32) w[threadIdx.x] = W2f[threadIdx.x];
    if (threadIdx.x < 2)  w[32 + threadIdx.x] = b2fv[threadIdx.x];
    __syncthreads();
    for (long b = (long)blockIdx.x * blockDim.x + threadIdx.x; b < B;
         b += (long)gridDim.x * blockDim.x) {
        const float* h = hbuf + b * 16;
        float l0 = w[32], l1 = w[33];
#pragma unroll
        for (int q = 0; q < 4; ++q) {
            float4 v = *(const float4*)&h[q * 4];
            l0 += w[q * 4] * v.x + w[q * 4 + 1] * v.y + w[q * 4 + 2] * v.z + w[q * 4 + 3] * v.w;
            l1 += w[16 + q * 4] * v.x + w[17 + q * 4] * v.y + w[18 + q * 4] * v.z + w[19 + q * 4] * v.w;
        }
        float m  = fmaxf(l0, l1);
        float e0 = __expf(l0 - m), e1 = __expf(l1 - m);
        float inv = frcp(e0 + e1);
        float2 p; p.x = e0 * inv; p.y = e1 * inv;
        *(float2*)&out[b * 2] = p;
    }
}

// ---------------------------------------------------------------------------
extern "C" void kernel_launch(void* const* d_in, const int* in_sizes, int n_in,
                              void* d_out, int out_size, void* d_ws, size_t ws_size,
                              hipStream_t stream)
{
    const int* user_id   = (const int*)d_in[0];
    const int* hist_item = (const int*)d_in[1];
    const int* hist_cat  = (const int*)d_in[2];
    const int* tgt_item  = (const int*)d_in[3];
    const int* tgt_cat   = (const int*)d_in[4];
    fp user_table = (fp)d_in[5];
    fp item_table = (fp)d_in[6];
    fp cat_table  = (fp)d_in[7];
    fp Wih = (fp)d_in[8],  Whh = (fp)d_in[9];
    fp bih = (fp)d_in[10], bhh = (fp)d_in[11];
    fp Win = (fp)d_in[12], binp = (fp)d_in[13];
    fp Wout = (fp)d_in[14], bout = (fp)d_in[15];
    fp g1 = (fp)d_in[16], b1 = (fp)d_in[17];
    fp fc1W = (fp)d_in[18], fc1b = (fp)d_in[19];
    fp g2 = (fp)d_in[20], b2 = (fp)d_in[21];
    fp fc2W = (fp)d_in[22], fc2b = (fp)d_in[23];

    const int B = in_sizes[0];
    const int T = in_sizes[1] / B;
    const int nItem = in_sizes[6] / 12;   // 10000
    const int nItemElems = nItem * 48;

    float* ws      = (float*)d_ws;
    float* P_item  = ws;                              // nItem*48
    float* P_cat   = P_item + (size_t)nItemElems;     // 520 (10 x 52 padded)
    float* stats   = P_cat + 520;                     // 128 (BN1 96 + BN2 32)
    float* stats2  = stats + 96;
    float* W1f     = stats + 128;                     // 768
    float* b1f     = W1f + 768;                       // 16
    float* W2f     = b1f + 16;                        // 32
    float* b2fv    = W2f + 32;                        // 2
    float* all_enc = b2fv + 2 + 2;                    // pad to 16B; B*48
    float* hbuf    = all_enc + (size_t)B * 48;        // B*16

    const int nItemBlocks = (nItemElems + 255) / 256;
    hipLaunchKernelGGL(k_precompute, dim3(nItemBlocks + 1), dim3(256), 0, stream,
                       Wih, bih, bhh, item_table, cat_table, P_item, P_cat, stats,
                       nItemElems, nItemBlocks);

    hipLaunchKernelGGL(k_gru, dim3((B + 63) / 64), dim3(256), 0, stream,
                       user_id, hist_item, hist_cat, tgt_item, tgt_cat,
                       user_table, item_table, cat_table, Whh, bhh,
                       Win, binp, Wout, bout, P_item, P_cat,
                       all_enc, stats, B, T);

    hipLaunchKernelGGL(k_fold1, dim3(1), dim3(256), 0, stream,
                       stats, fc1W, fc1b, g1, b1, W1f, b1f, B);

    hipLaunchKernelGGL(k_fc1, dim3(512), dim3(256), 0, stream,
                       all_enc, W1f, b1f, hbuf, stats2, B);

    hipLaunchKernelGGL(k_fold2, dim3(1), dim3(64), 0, stream,
                       stats2, fc2W, fc2b, g2, b2, W2f, b2fv, B);

    hipLaunchKernelGGL(k_out, dim3((B + 255) / 256), dim3(256), 0, stream,
                       hbuf, W2f, b2fv, (float*)d_out, B);
}

// Round 3
// 82.287 us; speedup vs baseline: 1.3349x; 1.0269x over previous
//
#include <hip/hip_runtime.h>

#define BN_EPS 1e-5f

typedef const float* fp;
typedef float f32x4 __attribute__((ext_vector_type(4)));
typedef _Float16 f16x2 __attribute__((ext_vector_type(2)));
typedef _Float16 f16x4 __attribute__((ext_vector_type(4)));
typedef _Float16 f16x8 __attribute__((ext_vector_type(8)));

// fast transcendentals: identical formulas to the previous (passing) kernel.
__device__ __forceinline__ float frcp(float x) { return __builtin_amdgcn_rcpf(x); }
__device__ __forceinline__ float sigm(float x) { return frcp(1.0f + __expf(-x)); }
__device__ __forceinline__ float tanh_fast(float x) { return 1.0f - 2.0f * frcp(1.0f + __expf(2.0f * x)); }

__device__ __forceinline__ f32x4 ld4(const float* p) { return *(const f32x4*)p; }
__device__ __forceinline__ float dot4(f32x4 a, f32x4 b) {
    return a[0] * b[0] + a[1] * b[1] + a[2] * b[2] + a[3] * b[3];
}

#define MFMA16(A, B, C) __builtin_amdgcn_mfma_f32_16x16x16f16((A), (B), (C), 0, 0, 0)
#define MFMA32(A, B, C) __builtin_amdgcn_mfma_f32_16x16x32_f16((A), (B), (C), 0, 0, 0)

// pack f32x4 -> f16x4 via v_cvt_pkrtz (2 inst). RTZ is fine: the lo-residual
// term absorbs the rounding, the pair (h_h, h_l) stays an exact split.
// (builtin returns __fp16 vec2 — bit_cast to our _Float16 vec2, same bits)
__device__ __forceinline__ f16x4 pk_f16(f32x4 v) {
    f16x2 lo = __builtin_bit_cast(f16x2, __builtin_amdgcn_cvt_pkrtz(v[0], v[1]));
    f16x2 hi = __builtin_bit_cast(f16x2, __builtin_amdgcn_cvt_pkrtz(v[2], v[3]));
    return __builtin_shufflevector(lo, hi, 0, 1, 2, 3);
}

// ---------------------------------------------------------------------------
// K1: fold item/cat embedding tables through Wih; zero the BN stats accums.
// P_cat rows padded to 52 floats and carry bih (+ bhh for the r,z gates).
// ---------------------------------------------------------------------------
__global__ __launch_bounds__(256) void k_precompute(
    fp Wih, fp bih, fp bhh, fp item_table, fp cat_table,
    float* __restrict__ P_item, float* __restrict__ P_cat,
    float* __restrict__ stats, int nItemElems, int nItemBlocks)
{
    __shared__ float w[768];
    for (int t = threadIdx.x; t < 768; t += blockDim.x) w[t] = Wih[t];
    __syncthreads();

    if ((int)blockIdx.x < nItemBlocks) {
        int idx = blockIdx.x * blockDim.x + threadIdx.x;
        if (idx < nItemElems) {
            int i = idx / 48, g = idx % 48;
            const float* row = item_table + (size_t)i * 12;
            float acc = 0.f;
#pragma unroll
            for (int k = 0; k < 12; ++k) acc += w[g * 16 + k] * row[k];
            P_item[idx] = acc;
        }
    } else {
        for (int t = threadIdx.x; t < 480; t += blockDim.x) {
            int c = t / 48, g = t % 48;
            float acc = bih[g] + (g < 32 ? bhh[g] : 0.f);
#pragma unroll
            for (int k = 0; k < 4; ++k) acc += w[g * 16 + 12 + k] * cat_table[c * 4 + k];
            P_cat[c * 52 + g] = acc;
        }
        if (threadIdx.x < 128) stats[threadIdx.x] = 0.f;   // stats1[96] + stats2[32]
    }
}

// ---------------------------------------------------------------------------
// K2: MFMA GRU. One wave = 16 samples. Lane l: sample s=l&15, hi=l>>4.
// Per gate: one 16x16x32 MFMA with A=[W_hi|W_lo], B=[h_hi|h_hi] (both terms
// in one instruction; A/B share the slot->k map so pairing is exact), plus
// one chained 16x16x16 for the W_hi*h_lo residual. D layout == next B layout,
// so the recurrence has zero cross-lane traffic. 2-deep load pipeline.
// ---------------------------------------------------------------------------
__device__ __forceinline__ void gru_step(
    const f16x8& wrA, const f16x8& wzA, const f16x8& wnA,
    const f16x4& wrh, const f16x4& wzh, const f16x4& wnh,
    const f32x4& bhn4, f32x4 xr, f32x4 xz, f32x4 xn,
    f32x4& h, f32x4& hsum, f16x4& h_h, f16x4& h_l)
{
    f16x8 hB = __builtin_shufflevector(h_h, h_h, 0, 1, 2, 3, 0, 1, 2, 3);
    f32x4 aR = MFMA32(wrA, hB, xr);
    f32x4 aZ = MFMA32(wzA, hB, xz);
    f32x4 aN = MFMA32(wnA, hB, bhn4);
    aR = MFMA16(wrh, h_l, aR);
    aZ = MFMA16(wzh, h_l, aZ);
    aN = MFMA16(wnh, h_l, aN);
#pragma unroll
    for (int q = 0; q < 4; ++q) {
        float r = sigm(aR[q]);
        float z = sigm(aZ[q]);
        float n = tanh_fast(fmaf(r, aN[q], xn[q]));
        h[q] = z * (h[q] - n) + n;
    }
    hsum += h;
    h_h = pk_f16(h);
    f32x4 hb;
#pragma unroll
    for (int q = 0; q < 4; ++q) hb[q] = (float)h_h[q];
    h_l = pk_f16(h - hb);
}

__global__ __launch_bounds__(256) void k_gru(
    const int* __restrict__ user_id, const int* __restrict__ hist_item,
    const int* __restrict__ hist_cat, const int* __restrict__ tgt_item,
    const int* __restrict__ tgt_cat,
    fp user_table, fp item_table, fp cat_table,
    fp Whh, fp bhh,
    fp mha_Win, fp mha_bin, fp mha_Wout, fp mha_bout,
    const float* __restrict__ P_item, const float* __restrict__ P_cat,
    float* __restrict__ all_enc, float* __restrict__ stats1, int B, int T)
{
    __shared__ float s_pcat[520];       // 10 cats x 52 (padded)
    __shared__ float lds_part[4][96];

    const int tid  = threadIdx.x;
    const int lane = tid & 63;
    const int wid  = tid >> 6;
    const int s    = lane & 15;     // sample slot within wave
    const int hi   = lane >> 4;     // 4-dim group owned by this lane

    long b = ((long)blockIdx.x * 4 + wid) * 16 + s;
    const bool act = (b < B);
    if (!act) b = B - 1;            // clamp: loads stay valid, stores masked

    for (int t = tid; t < 520; t += 256) s_pcat[t] = P_cat[t];

    // prefetch epilogue indices early (independent of the recurrence)
    const int ti  = tgt_item[b];
    const int tc  = tgt_cat[b];
    const int uid = user_id[b];

    // Whh A-fragments (row = s, k = 4hi+i) per gate, split into f16 hi/lo
    f32x4 wrf = ld4(&Whh[(0  + s) * 16 + 4 * hi]);
    f32x4 wzf = ld4(&Whh[(16 + s) * 16 + 4 * hi]);
    f32x4 wnf = ld4(&Whh[(32 + s) * 16 + 4 * hi]);
    f16x4 wrh = __builtin_convertvector(wrf, f16x4);
    f16x4 wzh = __builtin_convertvector(wzf, f16x4);
    f16x4 wnh = __builtin_convertvector(wnf, f16x4);
    f16x4 wrl = __builtin_convertvector(wrf - __builtin_convertvector(wrh, f32x4), f16x4);
    f16x4 wzl = __builtin_convertvector(wzf - __builtin_convertvector(wzh, f32x4), f16x4);
    f16x4 wnl = __builtin_convertvector(wnf - __builtin_convertvector(wnh, f32x4), f16x4);
    f16x8 wrA = __builtin_shufflevector(wrh, wrl, 0, 1, 2, 3, 4, 5, 6, 7);
    f16x8 wzA = __builtin_shufflevector(wzh, wzl, 0, 1, 2, 3, 4, 5, 6, 7);
    f16x8 wnA = __builtin_shufflevector(wnh, wnl, 0, 1, 2, 3, 4, 5, 6, 7);
    const f32x4 bhn4 = ld4(&bhh[32 + 4 * hi]);   // C-init of the n-gate MFMA

    const int* ip = hist_item + b * T;
    const int* cp = hist_cat  + b * T;

    f32x4 h    = {0.f, 0.f, 0.f, 0.f};
    f32x4 hsum = {0.f, 0.f, 0.f, 0.f};
    f16x4 h_h = {}, h_l = {};

    __syncthreads();   // s_pcat ready

    // ---- 2-deep pipelined recurrence (A = even steps, B = odd steps) ----
    f32x4 pirA, pizA, pinA, pcrA, pczA, pcnA;
    f32x4 pirB, pizB, pinB, pcrB, pczB, pcnB;

#define ISSUE_A(idv, cdv) { const float* pi_ = P_item + (unsigned)(idv) * 48u; \
    int pb_ = (cdv) * 52; \
    pirA = ld4(pi_ + 4 * hi); pizA = ld4(pi_ + 16 + 4 * hi); pinA = ld4(pi_ + 32 + 4 * hi); \
    pcrA = ld4(&s_pcat[pb_ + 4 * hi]); pczA = ld4(&s_pcat[pb_ + 16 + 4 * hi]); pcnA = ld4(&s_pcat[pb_ + 32 + 4 * hi]); }
#define ISSUE_B(idv, cdv) { const float* pi_ = P_item + (unsigned)(idv) * 48u; \
    int pb_ = (cdv) * 52; \
    pirB = ld4(pi_ + 4 * hi); pizB = ld4(pi_ + 16 + 4 * hi); pinB = ld4(pi_ + 32 + 4 * hi); \
    pcrB = ld4(&s_pcat[pb_ + 4 * hi]); pczB = ld4(&s_pcat[pb_ + 16 + 4 * hi]); pcnB = ld4(&s_pcat[pb_ + 32 + 4 * hi]); }

    const int tl = T - 1;
    int idA = ip[0], cdA = cp[0];
    ISSUE_A(idA, cdA);                       // loads for step 0
    int i1 = 1 <= tl ? 1 : tl;
    int idB = ip[i1], cdB = cp[i1];
    ISSUE_B(idB, cdB);                       // loads for step 1
    int i2 = 2 <= tl ? 2 : tl;
    idA = ip[i2]; cdA = cp[i2];              // indices for step 2 issue
    int i3 = 3 <= tl ? 3 : tl;
    idB = ip[i3]; cdB = cp[i3];              // indices for step 3 issue

    const int Teven = T & ~1;
    for (int t = 0; t < Teven; t += 2) {
        // step t (A set)
        f32x4 xr = pirA + pcrA, xz = pizA + pczA, xn = pinA + pcnA;
        ISSUE_A(idA, cdA);                   // loads for t+2
        { int tn = t + 4; if (tn > tl) tn = tl; idA = ip[tn]; cdA = cp[tn]; }
        gru_step(wrA, wzA, wnA, wrh, wzh, wnh, bhn4, xr, xz, xn, h, hsum, h_h, h_l);

        // step t+1 (B set)
        xr = pirB + pcrB; xz = pizB + pczB; xn = pinB + pcnB;
        ISSUE_B(idB, cdB);                   // loads for t+3
        { int tn = t + 5; if (tn > tl) tn = tl; idB = ip[tn]; cdB = cp[tn]; }
        gru_step(wrA, wzA, wnA, wrh, wzh, wnh, bhn4, xr, xz, xn, h, hsum, h_h, h_l);
    }
    if (T & 1) {
        f32x4 xr = pirA + pcrA, xz = pizA + pczA, xn = pinA + pcnA;
        gru_step(wrA, wzA, wnA, wrh, wzh, wnh, bhn4, xr, xz, xn, h, hsum, h_h, h_l);
    }
#undef ISSUE_A
#undef ISSUE_B

    // ---- epilogue: degenerate MHA -> A[b], all_enc row, BN1 stats ----
    const float* itr = item_table + (size_t)ti * 12;
    f32x4 tv0 = ld4(itr), tv1 = ld4(itr + 4), tv2 = ld4(itr + 8);
    f32x4 tv3 = ld4(cat_table + tc * 4);

    // v = Wv @ tgt + bv  (rows 32..47 of mha_Win); lane computes dims 4hi+q
    f32x4 vq;
#pragma unroll
    for (int q = 0; q < 4; ++q) {
        int row = 32 + 4 * hi + q;
        const float* wv = mha_Win + row * 16;
        vq[q] = mha_bin[row] + dot4(ld4(wv), tv0) + dot4(ld4(wv + 4), tv1)
              + dot4(ld4(wv + 8), tv2) + dot4(ld4(wv + 12), tv3);
    }
    // gather full v[16] of this sample from the 4 hi-groups (lanes s+16g)
    f32x4 vg0, vg1, vg2, vg3;
#pragma unroll
    for (int q = 0; q < 4; ++q) {
        vg0[q] = __shfl_xor(vq[q], (hi ^ 0) << 4);
        vg1[q] = __shfl_xor(vq[q], (hi ^ 1) << 4);
        vg2[q] = __shfl_xor(vq[q], (hi ^ 2) << 4);
        vg3[q] = __shfl_xor(vq[q], (hi ^ 3) << 4);
    }
    f32x4 aj;
#pragma unroll
    for (int q = 0; q < 4; ++q) {
        int row = 4 * hi + q;
        const float* wo = mha_Wout + row * 16;
        aj[q] = mha_bout[row] + dot4(ld4(wo), vg0) + dot4(ld4(wo + 4), vg1)
              + dot4(ld4(wo + 8), vg2) + dot4(ld4(wo + 12), vg3);
    }
    f32x4 avg = aj * hsum;

    f32x4 u4 = ld4(user_table + (size_t)uid * 16 + 4 * hi);
    f32x4 t4 = (hi == 0) ? tv0 : (hi == 1) ? tv1 : (hi == 2) ? tv2 : tv3;

    if (act) {
        float* er = all_enc + b * 48 + 4 * hi;
        *(f32x4*)er        = avg;
        *(f32x4*)(er + 16) = t4;
        *(f32x4*)(er + 32) = u4;
    }

    f32x4 sa = avg, st = t4, su = u4;
    if (!act) {
        sa = (f32x4){0.f, 0.f, 0.f, 0.f};
        st = (f32x4){0.f, 0.f, 0.f, 0.f};
        su = (f32x4){0.f, 0.f, 0.f, 0.f};
    }
    f32x4 qa = sa * sa, qt = st * st, qu = su * su;
    // reduce over the 16 samples of this wave (xor over lane&15)
#pragma unroll
    for (int m = 1; m <= 8; m <<= 1) {
#pragma unroll
        for (int q = 0; q < 4; ++q) {
            sa[q] += __shfl_xor(sa[q], m);
            st[q] += __shfl_xor(st[q], m);
            su[q] += __shfl_xor(su[q], m);
            qa[q] += __shfl_xor(qa[q], m);
            qt[q] += __shfl_xor(qt[q], m);
            qu[q] += __shfl_xor(qu[q], m);
        }
    }
    if (s == 0) {
        int c = 4 * hi;
#pragma unroll
        for (int q = 0; q < 4; ++q) {
            lds_part[wid][c + q]      = sa[q];
            lds_part[wid][16 + c + q] = st[q];
            lds_part[wid][32 + c + q] = su[q];
            lds_part[wid][48 + c + q] = qa[q];
            lds_part[wid][64 + c + q] = qt[q];
            lds_part[wid][80 + c + q] = qu[q];
        }
    }
    __syncthreads();
    if (tid < 96) {
        float v = lds_part[0][tid] + lds_part[1][tid] + lds_part[2][tid] + lds_part[3][tid];
        atomicAdd(&stats1[tid], v);
    }
}

// ---------------------------------------------------------------------------
// K3: fc1 with BN1-fold computed inline per block (saves a launch).
// h = relu(W1f @ all_enc + b1f), store h[B][16], accumulate BN2 stats.
// ---------------------------------------------------------------------------
__global__ __launch_bounds__(256) void k_fc1(
    const float* __restrict__ all_enc, const float* __restrict__ stats,
    fp fc1_W, fp fc1_b, fp g1, fp b1,
    float* __restrict__ hbuf, float* __restrict__ stats2, int B)
{
    const int tid = threadIdx.x, lane = tid & 63, wid = tid >> 6;
    const int j = lane & 15, sl = lane >> 4;
    __shared__ float kk[48], mm[48];
    __shared__ float part[4][32];

    if (tid < 48) {
        float mu  = stats[tid] / (float)B;
        float var = stats[48 + tid] / (float)B - mu * mu;
        float k   = rsqrtf(var + BN_EPS);
        float gk  = g1[tid] * k;
        kk[tid] = gk;
        mm[tid] = b1[tid] - mu * gk;
    }
    __syncthreads();

    float w[48];
    float bj = fc1_b[j];
#pragma unroll
    for (int q = 0; q < 12; ++q) {
        float4 v = *(const float4*)&fc1_W[j * 48 + q * 4];
        w[q * 4 + 0] = v.x * kk[q * 4 + 0];
        w[q * 4 + 1] = v.y * kk[q * 4 + 1];
        w[q * 4 + 2] = v.z * kk[q * 4 + 2];
        w[q * 4 + 3] = v.w * kk[q * 4 + 3];
        bj += v.x * mm[q * 4 + 0] + v.y * mm[q * 4 + 1]
            + v.z * mm[q * 4 + 2] + v.w * mm[q * 4 + 3];
    }

    float sh = 0.f, sq = 0.f;
    for (long b = (long)blockIdx.x * 16 + wid * 4 + sl; b < B; b += (long)gridDim.x * 16) {
        const float* x = all_enc + b * 48;
        float acc = bj;
#pragma unroll
        for (int q = 0; q < 12; ++q) {
            float4 v = *(const float4*)&x[q * 4];
            acc += w[q * 4] * v.x + w[q * 4 + 1] * v.y + w[q * 4 + 2] * v.z + w[q * 4 + 3] * v.w;
        }
        float h = fmaxf(acc, 0.f);
        hbuf[b * 16 + j] = h;
        sh += h; sq += h * h;
    }
    sh += __shfl_xor(sh, 16); sh += __shfl_xor(sh, 32);
    sq += __shfl_xor(sq, 16); sq += __shfl_xor(sq, 32);
    if (sl == 0) { part[wid][j] = sh; part[wid][16 + j] = sq; }
    __syncthreads();
    if (tid < 32) {
        float v = part[0][tid] + part[1][tid] + part[2][tid] + part[3][tid];
        atomicAdd(&stats2[tid], v);
    }
}

// ---------------------------------------------------------------------------
// K4: logits + softmax, BN2-fold computed inline per block (saves a launch).
// ---------------------------------------------------------------------------
__global__ __launch_bounds__(256) void k_out(
    const float* __restrict__ hbuf, const float* __restrict__ stats2,
    fp fc2_W, fp fc2_b, fp g2, fp b2, float* __restrict__ out, int B)
{
    __shared__ float w[34];
    const int tid = threadIdx.x;
    if (tid < 32) {
        int c = tid & 15;
        float mu  = stats2[c] / (float)B;
        float var = stats2[16 + c] / (float)B - mu * mu;
        float gk  = g2[c] * rsqrtf(var + BN_EPS);
        w[tid] = fc2_W[tid] * gk;
    }
    if (tid < 2) {
        float acc = fc2_b[tid];
        for (int c = 0; c < 16; ++c) {
            float mu  = stats2[c] / (float)B;
            float var = stats2[16 + c] / (float)B - mu * mu;
            float gk  = g2[c] * rsqrtf(var + BN_EPS);
            acc += fc2_W[tid * 16 + c] * (b2[c] - mu * gk);
        }
        w[32 + tid] = acc;
    }
    __syncthreads();
    for (long b = (long)blockIdx.x * blockDim.x + threadIdx.x; b < B;
         b += (long)gridDim.x * blockDim.x) {
        const float* h = hbuf + b * 16;
        float l0 = w[32], l1 = w[33];
#pragma unroll
        for (int q = 0; q < 4; ++q) {
            float4 v = *(const float4*)&h[q * 4];
            l0 += w[q * 4] * v.x + w[q * 4 + 1] * v.y + w[q * 4 + 2] * v.z + w[q * 4 + 3] * v.w;
            l1 += w[16 + q * 4] * v.x + w[17 + q * 4] * v.y + w[18 + q * 4] * v.z + w[19 + q * 4] * v.w;
        }
        float m  = fmaxf(l0, l1);
        float e0 = __expf(l0 - m), e1 = __expf(l1 - m);
        float inv = frcp(e0 + e1);
        float2 p; p.x = e0 * inv; p.y = e1 * inv;
        *(float2*)&out[b * 2] = p;
    }
}

// ---------------------------------------------------------------------------
extern "C" void kernel_launch(void* const* d_in, const int* in_sizes, int n_in,
                              void* d_out, int out_size, void* d_ws, size_t ws_size,
                              hipStream_t stream)
{
    const int* user_id   = (const int*)d_in[0];
    const int* hist_item = (const int*)d_in[1];
    const int* hist_cat  = (const int*)d_in[2];
    const int* tgt_item  = (const int*)d_in[3];
    const int* tgt_cat   = (const int*)d_in[4];
    fp user_table = (fp)d_in[5];
    fp item_table = (fp)d_in[6];
    fp cat_table  = (fp)d_in[7];
    fp Wih = (fp)d_in[8],  Whh = (fp)d_in[9];
    fp bih = (fp)d_in[10], bhh = (fp)d_in[11];
    fp Win = (fp)d_in[12], binp = (fp)d_in[13];
    fp Wout = (fp)d_in[14], bout = (fp)d_in[15];
    fp g1 = (fp)d_in[16], b1 = (fp)d_in[17];
    fp fc1W = (fp)d_in[18], fc1b = (fp)d_in[19];
    fp g2 = (fp)d_in[20], b2 = (fp)d_in[21];
    fp fc2W = (fp)d_in[22], fc2b = (fp)d_in[23];

    const int B = in_sizes[0];
    const int T = in_sizes[1] / B;
    const int nItem = in_sizes[6] / 12;   // 10000
    const int nItemElems = nItem * 48;

    float* ws      = (float*)d_ws;
    float* P_item  = ws;                              // nItem*48
    float* P_cat   = P_item + (size_t)nItemElems;     // 520 (10 x 52 padded)
    float* stats   = P_cat + 520;                     // 128 (BN1 96 + BN2 32)
    float* stats2  = stats + 96;
    float* all_enc = stats + 128 + 8;                 // pad to 16B; B*48
    float* hbuf    = all_enc + (size_t)B * 48;        // B*16

    const int nItemBlocks = (nItemElems + 255) / 256;
    hipLaunchKernelGGL(k_precompute, dim3(nItemBlocks + 1), dim3(256), 0, stream,
                       Wih, bih, bhh, item_table, cat_table, P_item, P_cat, stats,
                       nItemElems, nItemBlocks);

    hipLaunchKernelGGL(k_gru, dim3((B + 63) / 64), dim3(256), 0, stream,
                       user_id, hist_item, hist_cat, tgt_item, tgt_cat,
                       user_table, item_table, cat_table, Whh, bhh,
                       Win, binp, Wout, bout, P_item, P_cat,
                       all_enc, stats, B, T);

    hipLaunchKernelGGL(k_fc1, dim3(512), dim3(256), 0, stream,
                       all_enc, stats, fc1W, fc1b, g1, b1, hbuf, stats2, B);

    hipLaunchKernelGGL(k_out, dim3((B + 255) / 256), dim3(256), 0, stream,
                       hbuf, stats2, fc2W, fc2b, g2, b2, (float*)d_out, B);
}